// Round 6
// baseline (300.549 us; speedup 1.0000x reference)
//
#include <hip/hip_runtime.h>

constexpr int N_NODES  = 50000;
constexpr int N_EDGES  = 1600000;
constexpr int F_IN     = 48;
constexpr int C1_OUT   = 16;
constexpr int AGG_BLKS = N_NODES / 4;          // 12500, wave-per-node, 4 waves/block
constexpr int STRIDE   = 96;                   // in-deg ~ Poisson(32); P(deg>=96) ~ 1e-29 -> safe
constexpr int SLICE_N  = N_NODES / 8;          // 6250 nodes per XCD slice
constexpr int CHUNK    = 2560;                 // edges per work chunk (10 iters x 256 thr)
constexpr int NCHUNKS  = N_EDGES / CHUNK;      // 625 chunks per slice
constexpr int FILL_BLKS = 1024;                // fill workers (work-stealing)
constexpr int XW_BLKS   = (N_NODES + 255) / 256;  // 196

// ---- direct-path ws layout --------------------------------------------------
constexpr size_t CNT_BYTES  = (size_t)N_NODES * sizeof(int);            // 200000
constexpr size_t WCTR_BYTES = 8 * sizeof(int);                          // 32
constexpr size_t PART_BYTES = (size_t)AGG_BLKS * sizeof(float);         // 50000
constexpr size_t XW_BYTES   = (size_t)N_NODES * C1_OUT * sizeof(float); // 3.2e6
constexpr size_t BKD_BYTES  = (size_t)N_NODES * STRIDE * sizeof(int);   // 19.2e6
constexpr size_t NEED_DIRECT = CNT_BYTES + WCTR_BYTES + PART_BYTES + XW_BYTES + BKD_BYTES;
// ---- fallback (CSR) ws layout ----------------------------------------------
constexpr size_t RS_BYTES   = ((size_t)(N_NODES + 1) * sizeof(int) + 15) & ~(size_t)15;
constexpr size_t BKF_BYTES  = (size_t)N_EDGES * sizeof(int);

// ---------------------------------------------------------------------------
// xw[n] = x[n] @ W  (fold linear map before gather; 3.2 MB table, L2-resident)
// ---------------------------------------------------------------------------
__device__ __forceinline__ void xw_body(int n, const float* __restrict__ x,
                                        const float* __restrict__ W,
                                        float* __restrict__ xw)
{
    const float4* xr = (const float4*)(x + (long)n * F_IN);
    float h[C1_OUT];
    #pragma unroll
    for (int c = 0; c < C1_OUT; ++c) h[c] = 0.f;
    #pragma unroll
    for (int k = 0; k < F_IN / 4; ++k) {
        float4 v = xr[k];
        #pragma unroll
        for (int c = 0; c < C1_OUT; ++c) {
            h[c] = fmaf(v.x, W[(4*k+0)*C1_OUT + c],
                   fmaf(v.y, W[(4*k+1)*C1_OUT + c],
                   fmaf(v.z, W[(4*k+2)*C1_OUT + c],
                   fmaf(v.w, W[(4*k+3)*C1_OUT + c], h[c]))));
        }
    }
    float4* o = (float4*)(xw + (long)n * C1_OUT);
    o[0] = make_float4(h[0],  h[1],  h[2],  h[3]);
    o[1] = make_float4(h[4],  h[5],  h[6],  h[7]);
    o[2] = make_float4(h[8],  h[9],  h[10], h[11]);
    o[3] = make_float4(h[12], h[13], h[14], h[15]);
}

// ---------------------------------------------------------------------------
// XCD-sliced fill + fused xw.
// Each XCD's blocks prefer edges whose dst lies in the XCD's node slice, so a
// node's 384 B bucket row accumulates its writes inside ONE L2 (slice bucket =
// 2.4 MB, L2-resident) -> flush writes mostly-full lines instead of 64 B per
// edge (R4: WRITE_SIZE 102.7 MB ~= E x 64 B).
// R5 BUG FIX: chunk claiming is now PER BLOCK (lane 0 -> LDS -> barrier);
// R5 claimed per-thread, so each chunk was processed at 1/256 coverage.
// Work-stealing over per-slice chunk counters keeps coverage independent of
// the (undefined) block->XCD mapping.
// ---------------------------------------------------------------------------
__global__ __launch_bounds__(256)
void k_fill_xw(const int* __restrict__ src, const int* __restrict__ dst,
               int* __restrict__ cnt, int* __restrict__ wctr,
               int* __restrict__ bucket,
               const float* __restrict__ x, const float* __restrict__ W,
               float* __restrict__ xw)
{
    if (blockIdx.x >= FILL_BLKS) {            // xw tail blocks
        int n = (blockIdx.x - FILL_BLKS) * 256 + threadIdx.x;
        if (n < N_NODES) xw_body(n, x, W, xw);
        return;
    }

    __shared__ int sChunk;
    int xcd;
    asm volatile("s_getreg_b32 %0, hwreg(HW_REG_XCC_ID)" : "=s"(xcd));
    xcd &= 7;

    for (int t = 0; t < 8; ++t) {             // own slice first, then steal
        int sl = (xcd + t) & 7;
        int lo = sl * SLICE_N, hi = lo + SLICE_N;
        while (true) {
            if (threadIdx.x == 0) sChunk = atomicAdd(&wctr[sl], 1);
            __syncthreads();
            int c = sChunk;
            __syncthreads();                  // all reads done before next write
            if (c >= NCHUNKS) break;          // uniform
            int base = c * CHUNK + threadIdx.x;
            #pragma unroll
            for (int k = 0; k < CHUNK / 256; ++k) {
                int e = base + k * 256;
                int d = dst[e];               // coalesced; L3-resident after 1st scan
                if (d >= lo && d < hi) {
                    int s = src[e];
                    int pos = atomicAdd(&cnt[d], 1);
                    bucket[(long)d * STRIDE + pos] = s;
                }
            }
        }
    }
}

// ---------------------------------------------------------------------------
// Shared epilogue: mean + bias + relu -> 16->8 relu -> 8->1 sigmoid -> p,
// weighted BCE partial (stored per block — single-address fp atomics
// serialize; that was the R3 166us wall).
// ---------------------------------------------------------------------------
__device__ __forceinline__ void node_epilogue(
    float4 a, int n, float inv, const float* __restrict__ xw,
    const float* __restrict__ bias, const float* __restrict__ lin1_w,
    const float* __restrict__ lin1_b, const float* __restrict__ out_w,
    const float* __restrict__ out_b, const float* __restrict__ labels,
    const float* __restrict__ weights, float* __restrict__ out,
    float (&s16)[16], float (&sLoss), int lane)
{
    if (lane < 4) {
        float4 v  = ((const float4*)(xw + (long)n * C1_OUT))[lane]; // self loop
        float4 b4 = ((const float4*)bias)[lane];
        float4 h;
        h.x = fmaxf((a.x + v.x) * inv + b4.x, 0.f);
        h.y = fmaxf((a.y + v.y) * inv + b4.y, 0.f);
        h.z = fmaxf((a.z + v.z) * inv + b4.z, 0.f);
        h.w = fmaxf((a.w + v.w) * inv + b4.w, 0.f);
        ((float4*)&s16[0])[lane] = h;
    }
    // same-wave LDS dep: compiler inserts lgkmcnt wait; no barrier needed.
    float x2 = 0.f;
    if (lane < 8) {
        x2 = lin1_b[lane];
        #pragma unroll
        for (int k = 0; k < C1_OUT; ++k)
            x2 = fmaf(s16[k], lin1_w[k * 8 + lane], x2);
        x2 = fmaxf(x2, 0.f) * out_w[lane];
    }
    x2 += __shfl_xor(x2, 1, 64);
    x2 += __shfl_xor(x2, 2, 64);
    x2 += __shfl_xor(x2, 4, 64);
    if (lane == 0) {
        float z = x2 + out_b[0];
        float p = 1.f / (1.f + __expf(-z));
        out[1 + n] = p;
        const float eps = 1e-7f;
        float pc = fminf(fmaxf(p, eps), 1.f - eps);
        float y  = labels[n];
        float bce = -(y * __logf(pc) + (1.f - y) * __logf(1.f - pc));
        sLoss = weights[n] * bce;
    }
}

// ---------------------------------------------------------------------------
// Wave-per-node aggregate (unchanged — isolate the fill experiment).
// ---------------------------------------------------------------------------
__global__ __launch_bounds__(256)
void k_agg_direct(const float* __restrict__ xw, const int* __restrict__ cnt,
                  const int* __restrict__ bucket,
                  const float* __restrict__ bias, const float* __restrict__ lin1_w,
                  const float* __restrict__ lin1_b, const float* __restrict__ out_w,
                  const float* __restrict__ out_b, const float* __restrict__ labels,
                  const float* __restrict__ weights, float* __restrict__ out,
                  float* __restrict__ partials)
{
    __shared__ float s16[4][16];
    __shared__ float sLoss[4];
    int wave = threadIdx.x >> 6, lane = threadIdx.x & 63;
    int rslot = lane >> 2, c = lane & 3;
    int n = blockIdx.x * 4 + wave;

    int deg = cnt[n];
    const int* row = bucket + (long)n * STRIDE;
    float4 a = make_float4(0.f, 0.f, 0.f, 0.f);
    for (int j0 = 0; j0 < deg; j0 += 16) {
        int j = j0 + rslot;
        if (j < deg) {
            int s = row[j];
            float4 v = ((const float4*)(xw + (long)s * C1_OUT))[c];
            a.x += v.x; a.y += v.y; a.z += v.z; a.w += v.w;
        }
    }
    #pragma unroll
    for (int off = 4; off < 64; off <<= 1) {
        a.x += __shfl_xor(a.x, off, 64);
        a.y += __shfl_xor(a.y, off, 64);
        a.z += __shfl_xor(a.z, off, 64);
        a.w += __shfl_xor(a.w, off, 64);
    }
    node_epilogue(a, n, 1.f / (float)(deg + 1), xw, bias, lin1_w, lin1_b,
                  out_w, out_b, labels, weights, out, s16[wave], sLoss[wave], lane);
    __syncthreads();
    if (threadIdx.x == 0)
        partials[blockIdx.x] = sLoss[0] + sLoss[1] + sLoss[2] + sLoss[3];
}

__global__ __launch_bounds__(1024)
void k_loss_final(const float* __restrict__ partials, float* __restrict__ out)
{
    __shared__ float sw[16];
    int tid = threadIdx.x, lane = tid & 63, wv = tid >> 6;
    float s = 0.f;
    for (int i = tid; i < AGG_BLKS; i += 1024) s += partials[i];
    #pragma unroll
    for (int off = 32; off > 0; off >>= 1) s += __shfl_down(s, off, 64);
    if (lane == 0) sw[wv] = s;
    __syncthreads();
    if (tid == 0) {
        float t = 0.f;
        #pragma unroll
        for (int k = 0; k < 16; ++k) t += sw[k];
        out[0] = t / (float)N_NODES;
    }
}

// ======================= fallback (CSR) path ===============================
__global__ __launch_bounds__(256)
void k_xw(const float* __restrict__ x, const float* __restrict__ W,
          float* __restrict__ xw)
{
    int n = blockIdx.x * 256 + threadIdx.x;
    if (n < N_NODES) xw_body(n, x, W, xw);
}

__global__ __launch_bounds__(256)
void k_hist(const int* __restrict__ dst, int* __restrict__ deg)
{
    int e = blockIdx.x * 256 + threadIdx.x;
    if (e < N_EDGES) atomicAdd(&deg[dst[e]], 1);
}

__global__ __launch_bounds__(1024)
void k_scan(int* __restrict__ cursor, int* __restrict__ row_start)
{
    __shared__ int sWave[16];
    int tid = threadIdx.x, lane = tid & 63, wv = tid >> 6;
    int run = 0;
    for (int base = 0; base < N_NODES; base += 1024) {
        int i = base + tid;
        int v = (i < N_NODES) ? cursor[i] : 0;
        int s = v;
        #pragma unroll
        for (int off = 1; off < 64; off <<= 1) {
            int u = __shfl_up(s, off, 64);
            if (lane >= off) s += u;
        }
        if (lane == 63) sWave[wv] = s;
        __syncthreads();
        int woff = 0, total = 0;
        #pragma unroll
        for (int k = 0; k < 16; ++k) {
            int w = sWave[k];
            if (k < wv) woff += w;
            total += w;
        }
        int excl = run + woff + (s - v);
        if (i < N_NODES) { row_start[i] = excl; cursor[i] = excl; }
        run += total;
        __syncthreads();
    }
    if (tid == 0) row_start[N_NODES] = N_EDGES;
}

__global__ __launch_bounds__(256)
void k_fill(const int* __restrict__ src, const int* __restrict__ dst,
            int* __restrict__ cursor, int* __restrict__ bucket)
{
    int e = blockIdx.x * 256 + threadIdx.x;
    if (e < N_EDGES) {
        int pos = atomicAdd(&cursor[dst[e]], 1);
        bucket[pos] = src[e];
    }
}

__global__ __launch_bounds__(256)
void k_agg_csr(const float* __restrict__ xw, const int* __restrict__ row_start,
               const int* __restrict__ bucket,
               const float* __restrict__ bias, const float* __restrict__ lin1_w,
               const float* __restrict__ lin1_b, const float* __restrict__ out_w,
               const float* __restrict__ out_b, const float* __restrict__ labels,
               const float* __restrict__ weights, float* __restrict__ out,
               float* __restrict__ partials)
{
    __shared__ float s16[4][16];
    __shared__ float sLoss[4];
    int wave = threadIdx.x >> 6, lane = threadIdx.x & 63;
    int rslot = lane >> 2, c = lane & 3;
    int n = blockIdx.x * 4 + wave;

    int rs = row_start[n], re = row_start[n + 1];
    float4 a = make_float4(0.f, 0.f, 0.f, 0.f);
    for (int j0 = rs; j0 < re; j0 += 16) {
        int j = j0 + rslot;
        if (j < re) {
            int s = bucket[j];
            float4 v = ((const float4*)(xw + (long)s * C1_OUT))[c];
            a.x += v.x; a.y += v.y; a.z += v.z; a.w += v.w;
        }
    }
    #pragma unroll
    for (int off = 4; off < 64; off <<= 1) {
        a.x += __shfl_xor(a.x, off, 64);
        a.y += __shfl_xor(a.y, off, 64);
        a.z += __shfl_xor(a.z, off, 64);
        a.w += __shfl_xor(a.w, off, 64);
    }
    node_epilogue(a, n, 1.f / (float)(re - rs + 1), xw, bias, lin1_w, lin1_b,
                  out_w, out_b, labels, weights, out, s16[wave], sLoss[wave], lane);
    __syncthreads();
    if (threadIdx.x == 0)
        partials[blockIdx.x] = sLoss[0] + sLoss[1] + sLoss[2] + sLoss[3];
}

// ===========================================================================
extern "C" void kernel_launch(void* const* d_in, const int* in_sizes, int n_in,
                              void* d_out, int out_size, void* d_ws, size_t ws_size,
                              hipStream_t stream)
{
    const float* x       = (const float*)d_in[0];
    const int*   eidx    = (const int*)  d_in[1];   // [2, E]
    const float* labels  = (const float*)d_in[2];
    const float* weights = (const float*)d_in[3];
    const float* W       = (const float*)d_in[4];
    // d_in[5] = u, d_in[6] = c: dead — softmax over H=1 axis is identically 1
    const float* bias    = (const float*)d_in[7];
    const float* lin1_w  = (const float*)d_in[8];
    const float* lin1_b  = (const float*)d_in[9];
    const float* out_w   = (const float*)d_in[10];
    const float* out_b   = (const float*)d_in[11];
    float* out = (float*)d_out;

    const int* src = eidx;
    const int* dst = eidx + N_EDGES;
    char* ws = (char*)d_ws;

    if (ws_size >= NEED_DIRECT) {
        int*   cnt      = (int*)ws;
        int*   wctr     = (int*)(ws + CNT_BYTES);
        float* partials = (float*)(ws + CNT_BYTES + WCTR_BYTES);
        float* xw       = (float*)(ws + CNT_BYTES + WCTR_BYTES + PART_BYTES);
        int*   bucket   = (int*)(ws + CNT_BYTES + WCTR_BYTES + PART_BYTES + XW_BYTES);

        hipMemsetAsync(ws, 0, CNT_BYTES + WCTR_BYTES, stream);
        k_fill_xw<<<FILL_BLKS + XW_BLKS, 256, 0, stream>>>(
            src, dst, cnt, wctr, bucket, x, W, xw);
        k_agg_direct<<<AGG_BLKS, 256, 0, stream>>>(
            xw, cnt, bucket, bias, lin1_w, lin1_b, out_w, out_b,
            labels, weights, out, partials);
        k_loss_final<<<1, 1024, 0, stream>>>(partials, out);
    } else {
        int*   cursor    = (int*)ws;
        float* partials  = (float*)(ws + CNT_BYTES);
        int*   row_start = (int*)(ws + CNT_BYTES + PART_BYTES);
        int*   bucket    = (int*)(ws + CNT_BYTES + PART_BYTES + RS_BYTES);
        float* xw        = (float*)(ws + CNT_BYTES + PART_BYTES + RS_BYTES + BKF_BYTES);

        hipMemsetAsync(ws, 0, CNT_BYTES, stream);
        k_xw  <<<XW_BLKS, 256, 0, stream>>>(x, W, xw);
        k_hist<<<N_EDGES / 256, 256, 0, stream>>>(dst, cursor);
        k_scan<<<1, 1024, 0, stream>>>(cursor, row_start);
        k_fill<<<N_EDGES / 256, 256, 0, stream>>>(src, dst, cursor, bucket);
        k_agg_csr<<<AGG_BLKS, 256, 0, stream>>>(
            xw, row_start, bucket, bias, lin1_w, lin1_b, out_w, out_b,
            labels, weights, out, partials);
        k_loss_final<<<1, 1024, 0, stream>>>(partials, out);
    }
}